// Round 9
// baseline (119.942 us; speedup 1.0000x reference)
//
#include <hip/hip_runtime.h>
#include <hip/hip_bf16.h>

typedef __attribute__((ext_vector_type(8))) short bf16x8;
typedef __attribute__((ext_vector_type(4))) float f32x4;
typedef __attribute__((ext_vector_type(4))) unsigned short u16x4;
typedef __attribute__((ext_vector_type(2))) unsigned int u32x2;
typedef __attribute__((ext_vector_type(4))) unsigned int u32x4;
typedef __attribute__((ext_vector_type(4))) _Float16 f16x4;
typedef __attribute__((ext_vector_type(8))) _Float16 f16x8;
typedef __attribute__((ext_vector_type(2))) __fp16 h16x2;
typedef __attribute__((ext_vector_type(4))) __fp16 h16x4;

#define SEQ 2048
#define HD 64
#define BH 24

// round-half-up fp32 -> bf16; pack pair with v_perm
__device__ __forceinline__ unsigned bfpack(float a, float b) {
  union { float f; unsigned u; } ua, ub; ua.f = a; ub.f = b;
  return __builtin_amdgcn_perm(ub.u + 0x8000u, ua.u + 0x8000u, 0x07060302u);
}
__device__ __forceinline__ unsigned short f2bf(float f) {
  union { float f; unsigned u; } v; v.f = f;
  unsigned r = v.u + 0x7fffu + ((v.u >> 16) & 1u);
  return (unsigned short)(r >> 16);
}

// ---------------- fused prep: K tile -> bf16 row-major; V tile -> V^T f16
// (plain d x kt). One block per (k-tile, bh).
__global__ __launch_bounds__(256) void prep_kv(const float* __restrict__ K,
                                               const float* __restrict__ V,
                                               unsigned* __restrict__ Kb,
                                               _Float16* __restrict__ Vt) {
  __shared__ _Float16 t[64 * 68];
  const int bh = blockIdx.y;
  const int k0 = blockIdx.x * 64;
  const int tid = threadIdx.x;

  const float4* ks = (const float4*)(K + ((size_t)bh * SEQ + k0) * HD);
  unsigned* kd = Kb + ((size_t)bh * SEQ + k0) * (HD / 2);
#pragma unroll
  for (int i = 0; i < 4; ++i) {
    int f = tid + i * 256;
    float4 v = ks[f];
    u32x2 o;
    o.x = bfpack(v.x, v.y);
    o.y = bfpack(v.z, v.w);
    *(u32x2*)&kd[f * 2] = o;
  }

  const float4* vs = (const float4*)(V + ((size_t)bh * SEQ + k0) * HD);
#pragma unroll
  for (int i = 0; i < 4; ++i) {
    int f = tid + i * 256;
    int k = f >> 4, cg = f & 15;
    float4 v = vs[k * 16 + cg];
    int dg = cg * 4;
    t[(dg + 0) * 68 + k] = (_Float16)v.x;
    t[(dg + 1) * 68 + k] = (_Float16)v.y;
    t[(dg + 2) * 68 + k] = (_Float16)v.z;
    t[(dg + 3) * 68 + k] = (_Float16)v.w;
  }
  __syncthreads();
  int d = tid >> 2, kg = (tid & 3) * 16;
  _Float16* g = Vt + ((size_t)(bh * 64 + d)) * SEQ + k0 + kg;
#pragma unroll
  for (int r = 0; r < 4; ++r) {
    f16x4 x = *(f16x4*)&t[d * 68 + kg + r * 4];
    *(f16x4*)&g[r * 4] = x;
  }
}

// ---------------- main attention ----------------
// 8-wave blocks: wave w = (q-half w>>2, kt-quarter w&3). Same 16 KB K/V tile,
// triple-buffered DMA ring, vmcnt(2)+s_barrier pipeline. 24 waves/CU.
__global__ __launch_bounds__(512, 5) void attn_main(const float* __restrict__ Q,
                                                    const unsigned short* __restrict__ Kb,
                                                    const _Float16* __restrict__ Vt,
                                                    float* __restrict__ O) {
  __shared__ unsigned short kv[3][8192];  // K [0,4096) V [4096,8192) per buffer

  const int tid  = threadIdx.x;
  const int lane = tid & 63;
  const int w    = tid >> 6;   // 0..7
  const int kq   = w & 3;      // kt quarter
  const int qh   = w >> 2;     // q half
  const int quad = lane >> 4;
  const int n    = lane & 15;

  const int bh = blockIdx.x;
  const int q0 = blockIdx.y * 64;

  const float qscale = 0.125f * 1.44269504088896f; // 1/sqrt(64) * log2(e)

  // ---- Q B-frags for this wave's 2 q-subtiles
  bf16x8 qf[2][2];
#pragma unroll
  for (int u = 0; u < 2; ++u) {
    const float* qb = Q + ((size_t)bh * SEQ + q0 + qh * 32 + u * 16 + n) * HD;
#pragma unroll
    for (int h = 0; h < 2; ++h) {
      float4 a = *(const float4*)(qb + h * 32 + quad * 8);
      float4 b = *(const float4*)(qb + h * 32 + quad * 8 + 4);
      u32x4 pk;
      pk.x = bfpack(a.x * qscale, a.y * qscale);
      pk.y = bfpack(a.z * qscale, a.w * qscale);
      pk.z = bfpack(b.x * qscale, b.y * qscale);
      pk.w = bfpack(b.z * qscale, b.w * qscale);
      qf[u][h] = __builtin_bit_cast(bf16x8, pk);
    }
  }

  // ---- DMA: 1 K-slot + 1 V-slot per thread. slot s = tid (512 slots =
  // 64 rows x 8 granules of 16B): row r = s>>3, pos p = s&7, G = p^(r&7).
  const unsigned short* Kbase = Kb + (size_t)bh * SEQ * HD;
  const unsigned short* Vbase = (const unsigned short*)(Vt + (size_t)bh * HD * SEQ);
  const int r_ = tid >> 3, p_ = tid & 7, G_ = p_ ^ (r_ & 7);
  const unsigned short* ksrc = Kbase + r_ * HD + G_ * 8;
  const unsigned short* vsrc = Vbase + (size_t)r_ * SEQ + G_ * 8;
  const int soff = tid * 8;

#define DMA_TO(buf_, it_)                                                                 \
  {                                                                                       \
    unsigned short* db_ = &kv[buf_][0];                                                   \
    __builtin_amdgcn_global_load_lds(                                                     \
        (const __attribute__((address_space(1))) void*)(ksrc + (size_t)(it_) * 4096),     \
        (__attribute__((address_space(3))) void*)(db_ + soff), 16, 0, 0);                 \
    __builtin_amdgcn_global_load_lds(                                                     \
        (const __attribute__((address_space(1))) void*)(vsrc + (size_t)(it_) * 64),       \
        (__attribute__((address_space(3))) void*)(db_ + 4096 + soff), 16, 0, 0);          \
    asm volatile("" ::: "memory");                                                        \
  }

  f32x4 o[4][2];  // [dt][u]
#pragma unroll
  for (int dt = 0; dt < 4; ++dt)
#pragma unroll
    for (int u = 0; u < 2; ++u) o[dt][u] = (f32x4){0.f, 0.f, 0.f, 0.f};
  float lsum[2] = {0.f, 0.f};

  // K read offsets (own kt quarter): row kq*16+n, granule (h*4+quad)^(n&7)
  int ro[2];
#pragma unroll
  for (int h = 0; h < 2; ++h)
    ro[h] = (kq * 16 + n) * 64 + (((h * 4 + quad) ^ (n & 7)) * 8);
  // V read offsets (b64, f16 elems): row dt*16+n, kt = kq*16 + quad*4 + j
  int vo[4];
#pragma unroll
  for (int dt = 0; dt < 4; ++dt)
    vo[dt] = (dt * 16 + n) * 64 + (((kq * 2 + (quad >> 1)) ^ (n & 7)) * 8) + (quad & 1) * 4;

#define COMPUTE(buf_)                                                                     \
  {                                                                                       \
    const unsigned short* kb = &kv[buf_][0];                                              \
    const unsigned short* vb = kb + 4096;                                                 \
    f32x4 s[2] = {{0,0,0,0},{0,0,0,0}};                                                   \
    _Pragma("unroll")                                                                     \
    for (int h = 0; h < 2; ++h) {                                                         \
      bf16x8 a = *(const bf16x8*)&kb[ro[h]];                                              \
      _Pragma("unroll")                                                                   \
      for (int u = 0; u < 2; ++u)                                                         \
        s[u] = __builtin_amdgcn_mfma_f32_16x16x32_bf16(a, qf[u][h], s[u], 0, 0, 0);       \
    }                                                                                     \
    f16x4 pf[2];                                                                          \
    _Pragma("unroll")                                                                     \
    for (int u = 0; u < 2; ++u) {                                                         \
      float e0 = __builtin_amdgcn_exp2f(s[u][0]);                                         \
      float e1 = __builtin_amdgcn_exp2f(s[u][1]);                                         \
      float e2 = __builtin_amdgcn_exp2f(s[u][2]);                                         \
      float e3 = __builtin_amdgcn_exp2f(s[u][3]);                                         \
      lsum[u] += (e0 + e1) + (e2 + e3);                                                   \
      h16x2 a_ = __builtin_amdgcn_cvt_pkrtz(e0, e1);                                      \
      h16x2 b_ = __builtin_amdgcn_cvt_pkrtz(e2, e3);                                      \
      h16x4 ab_ = __builtin_shufflevector(a_, b_, 0, 1, 2, 3);                            \
      pf[u] = __builtin_bit_cast(f16x4, ab_);                                             \
    }                                                                                     \
    _Pragma("unroll")                                                                     \
    for (int dt = 0; dt < 4; ++dt) {                                                      \
      f16x4 vf = *(const f16x4*)((const _Float16*)vb + vo[dt]);                           \
      _Pragma("unroll")                                                                   \
      for (int u = 0; u < 2; ++u)                                                         \
        o[dt][u] = __builtin_amdgcn_mfma_f32_16x16x16f16(vf, pf[u], o[dt][u], 0, 0, 0);   \
    }                                                                                     \
  }

  DMA_TO(0, 0);
  DMA_TO(1, 1);

  int bc = 0;  // consume buffer (it % 3)
  int bd = 2;  // dma target ((it+2) % 3)
  for (int it = 0; it < 31; ++it) {
    // DMA(it)+DMA(it+1) outstanding (4 vm-instr/wave); vmcnt(2) drains DMA(it).
    asm volatile("s_waitcnt vmcnt(2)\n\ts_barrier" ::: "memory");
    if (it < 30) DMA_TO(bd, it + 2);
    COMPUTE(bc);
    bc = (bc == 2) ? 0 : bc + 1;
    bd = (bd == 2) ? 0 : bd + 1;
  }
  asm volatile("s_waitcnt vmcnt(0)\n\ts_barrier" ::: "memory");
  COMPUTE(bc);

#undef DMA_TO
#undef COMPUTE

  // ---- epilogue: reduce partial O/l across the 4 kt-quarters per q-half.
#pragma unroll
  for (int u = 0; u < 2; ++u) {
    lsum[u] += __shfl_xor(lsum[u], 16);
    lsum[u] += __shfl_xor(lsum[u], 32);
  }

  float* red = (float*)&kv[0][0];     // 4 slots x 2048 floats (O) = 32 KB
  float* lred = red + 4 * 2048;       // 4 slots x 128 floats (l)

  __syncthreads();
  if (kq >= 2) {
    int slot = qh * 2 + (kq - 2);
#pragma unroll
    for (int dt = 0; dt < 4; ++dt)
#pragma unroll
      for (int u = 0; u < 2; ++u)
        *(f32x4*)&red[slot * 2048 + (dt * 2 + u) * 256 + lane * 4] = o[dt][u];
#pragma unroll
    for (int u = 0; u < 2; ++u) lred[slot * 128 + u * 64 + lane] = lsum[u];
  }
  __syncthreads();
  if (kq < 2) {
    int slot = qh * 2 + kq;
#pragma unroll
    for (int dt = 0; dt < 4; ++dt)
#pragma unroll
      for (int u = 0; u < 2; ++u)
        o[dt][u] += *(f32x4*)&red[slot * 2048 + (dt * 2 + u) * 256 + lane * 4];
#pragma unroll
    for (int u = 0; u < 2; ++u) lsum[u] += lred[slot * 128 + u * 64 + lane];
  }
  __syncthreads();
  if (kq == 1) {
#pragma unroll
    for (int dt = 0; dt < 4; ++dt)
#pragma unroll
      for (int u = 0; u < 2; ++u)
        *(f32x4*)&red[qh * 2048 + (dt * 2 + u) * 256 + lane * 4] = o[dt][u];
#pragma unroll
    for (int u = 0; u < 2; ++u) lred[qh * 128 + u * 64 + lane] = lsum[u];
  }
  __syncthreads();
  if (kq == 0) {
#pragma unroll
    for (int u = 0; u < 2; ++u) {
      float ltot = lsum[u];
#pragma unroll
      for (int dt = 0; dt < 4; ++dt)
        o[dt][u] += *(f32x4*)&red[qh * 2048 + (dt * 2 + u) * 256 + lane * 4];
      ltot += lred[qh * 128 + u * 64 + lane];
      float inv = 1.0f / ltot;
      float* og = O + ((size_t)bh * SEQ + q0 + qh * 32 + u * 16 + n) * HD + quad * 4;
#pragma unroll
      for (int dt = 0; dt < 4; ++dt) {
        f32x4 r = o[dt][u];
        r.x *= inv; r.y *= inv; r.z *= inv; r.w *= inv;
        *(f32x4*)(og + dt * 16) = r;
      }
    }
  }
}

// ---------------- round-1 fallback (used only if ws too small) ----------------
#define F_QT 128
#define F_KT 64
#define F_LD 72

__global__ __launch_bounds__(512) void attn_fwd(const float* __restrict__ Q,
                                                const float* __restrict__ K,
                                                const float* __restrict__ V,
                                                float* __restrict__ O) {
  __shared__ unsigned short sm[(F_QT + F_KT + HD + 8 * 16) * F_LD];
  unsigned short* Qs = sm;
  unsigned short* Ks = Qs + F_QT * F_LD;
  unsigned short* Vt = Ks + F_KT * F_LD;
  unsigned short* Ps = Vt + HD * F_LD;

  const int tid = threadIdx.x, lane = tid & 63, wv = tid >> 6;
  const int quad = lane >> 4, n = lane & 15;
  const int bh = blockIdx.y, q0 = blockIdx.x * F_QT;
  const float* Qg = Q + ((size_t)bh * SEQ + q0) * HD;
  const float* Kg = K + (size_t)bh * SEQ * HD;
  const float* Vg = V + (size_t)bh * SEQ * HD;
  float* Og = O + ((size_t)bh * SEQ + q0) * HD;
  const float qscale = 0.125f * 1.44269504088896f;

#pragma unroll
  for (int i = 0; i < 4; ++i) {
    int f = tid + i * 512;
    int row = f >> 4, cg = f & 15;
    float4 qv = ((const float4*)Qg)[row * 16 + cg];
    u16x4 h;
    h.x = f2bf(qv.x * qscale); h.y = f2bf(qv.y * qscale);
    h.z = f2bf(qv.z * qscale); h.w = f2bf(qv.w * qscale);
    *(u16x4*)&Qs[row * F_LD + cg * 4] = h;
  }
  __syncthreads();
  bf16x8 qf0 = *(const bf16x8*)&Qs[(wv * 16 + n) * F_LD + quad * 8];
  bf16x8 qf1 = *(const bf16x8*)&Qs[(wv * 16 + n) * F_LD + 32 + quad * 8];
  f32x4 o[4] = {{0,0,0,0},{0,0,0,0},{0,0,0,0},{0,0,0,0}};
  float mrow[4] = {-1e30f,-1e30f,-1e30f,-1e30f};
  float lrow[4] = {0.f,0.f,0.f,0.f};
  unsigned short* Pw = Ps + wv * 16 * F_LD;

  for (int it = 0; it < SEQ / F_KT; ++it) {
    __syncthreads();
    const float* Ktg = Kg + (size_t)it * F_KT * HD;
    const float* Vtg = Vg + (size_t)it * F_KT * HD;
#pragma unroll
    for (int i = 0; i < 2; ++i) {
      int f = tid + i * 512;
      int row = f >> 4, cg = f & 15;
      float4 kvv = ((const float4*)Ktg)[row * 16 + cg];
      u16x4 hk;
      hk.x = f2bf(kvv.x); hk.y = f2bf(kvv.y); hk.z = f2bf(kvv.z); hk.w = f2bf(kvv.w);
      *(u16x4*)&Ks[row * F_LD + cg * 4] = hk;
      float4 vv = ((const float4*)Vtg)[row * 16 + cg];
      Vt[(cg * 4 + 0) * F_LD + row] = f2bf(vv.x);
      Vt[(cg * 4 + 1) * F_LD + row] = f2bf(vv.y);
      Vt[(cg * 4 + 2) * F_LD + row] = f2bf(vv.z);
      Vt[(cg * 4 + 3) * F_LD + row] = f2bf(vv.w);
    }
    __syncthreads();
    f32x4 s[4];
#pragma unroll
    for (int t = 0; t < 4; ++t) {
      bf16x8 b0 = *(const bf16x8*)&Ks[(t * 16 + n) * F_LD + quad * 8];
      bf16x8 b1 = *(const bf16x8*)&Ks[(t * 16 + n) * F_LD + 32 + quad * 8];
      f32x4 c = {0,0,0,0};
      c = __builtin_amdgcn_mfma_f32_16x16x32_bf16(qf0, b0, c, 0, 0, 0);
      c = __builtin_amdgcn_mfma_f32_16x16x32_bf16(qf1, b1, c, 0, 0, 0);
      s[t] = c;
    }
    float mnew[4], alpha[4], rsum[4];
#pragma unroll
    for (int r = 0; r < 4; ++r) {
      float ml = fmaxf(fmaxf(s[0][r], s[1][r]), fmaxf(s[2][r], s[3][r]));
      ml = fmaxf(ml, __shfl_xor(ml, 1));
      ml = fmaxf(ml, __shfl_xor(ml, 2));
      ml = fmaxf(ml, __shfl_xor(ml, 4));
      ml = fmaxf(ml, __shfl_xor(ml, 8));
      mnew[r] = fmaxf(mrow[r], ml);
      alpha[r] = __builtin_amdgcn_exp2f(mrow[r] - mnew[r]);
      mrow[r] = mnew[r];
      rsum[r] = 0.f;
    }
#pragma unroll
    for (int t = 0; t < 4; ++t)
#pragma unroll
      for (int r = 0; r < 4; ++r) {
        float p = __builtin_amdgcn_exp2f(s[t][r] - mnew[r]);
        rsum[r] += p;
        Pw[(quad * 4 + r) * F_LD + t * 16 + n] = f2bf(p);
      }
#pragma unroll
    for (int r = 0; r < 4; ++r) {
      float rs = rsum[r];
      rs += __shfl_xor(rs, 1); rs += __shfl_xor(rs, 2);
      rs += __shfl_xor(rs, 4); rs += __shfl_xor(rs, 8);
      lrow[r] = lrow[r] * alpha[r] + rs;
      o[0][r] *= alpha[r]; o[1][r] *= alpha[r];
      o[2][r] *= alpha[r]; o[3][r] *= alpha[r];
    }
    asm volatile("s_waitcnt lgkmcnt(0)" ::: "memory");
    bf16x8 p0 = *(const bf16x8*)&Pw[n * F_LD + quad * 8];
    bf16x8 p1 = *(const bf16x8*)&Pw[n * F_LD + 32 + quad * 8];
#pragma unroll
    for (int t = 0; t < 4; ++t) {
      bf16x8 v0 = *(const bf16x8*)&Vt[(t * 16 + n) * F_LD + quad * 8];
      bf16x8 v1 = *(const bf16x8*)&Vt[(t * 16 + n) * F_LD + 32 + quad * 8];
      o[t] = __builtin_amdgcn_mfma_f32_16x16x32_bf16(p0, v0, o[t], 0, 0, 0);
      o[t] = __builtin_amdgcn_mfma_f32_16x16x32_bf16(p1, v1, o[t], 0, 0, 0);
    }
  }
  float inv[4];
#pragma unroll
  for (int r = 0; r < 4; ++r) inv[r] = 1.0f / lrow[r];
#pragma unroll
  for (int t = 0; t < 4; ++t)
#pragma unroll
    for (int r = 0; r < 4; ++r)
      Og[(wv * 16 + quad * 4 + r) * HD + t * 16 + n] = o[t][r] * inv[r];
}

extern "C" void kernel_launch(void* const* d_in, const int* in_sizes, int n_in,
                              void* d_out, int out_size, void* d_ws, size_t ws_size,
                              hipStream_t stream) {
  const float* Q = (const float*)d_in[0];
  const float* K = (const float*)d_in[1];
  const float* V = (const float*)d_in[2];
  float* O = (float*)d_out;

  const size_t mat = (size_t)BH * SEQ * HD;
  const size_t need = 2 * mat * sizeof(unsigned short);  // K bf16 + V^T f16 = 12.6 MB

  if (ws_size >= need) {
    unsigned short* Kb = (unsigned short*)d_ws;
    _Float16* Vt = (_Float16*)(Kb + mat);
    prep_kv<<<dim3(SEQ / 64, BH), 256, 0, stream>>>(K, V, (unsigned*)Kb, Vt);
    attn_main<<<dim3(BH, SEQ / 64), 512, 0, stream>>>(Q, Kb, Vt, O);
  } else {
    attn_fwd<<<dim3(SEQ / F_QT, BH), 512, 0, stream>>>(Q, K, V, O);
  }
}